// Round 1
// baseline (1181.966 us; speedup 1.0000x reference)
//
#include <hip/hip_runtime.h>
#include <math.h>

#define BB 128
#define DD 256
#define SS 512
#define KK 50
#define HH 256
#define TS 32
#define NTILE (SS / TS)       // 16
#define NBLK (BB * NTILE)     // 2048
#define BS (BB * SS)          // 65536

// workspace layout (float offsets)
#define TVN_OFF 0
#define TPNT_OFF (TVN_OFF + DD * KK)     // 12800
#define PRED_OFF (TPNT_OFF + KK * BS)    // 12800 + 3276800
#define AE_OFF (PRED_OFF + BB * DD)
#define SIM_OFF (AE_OFF + 1)

// out layout: pred[0:256), 0.0@256, sim@257, far@258, nn[259:259+3276800), ae@3277059
#define OUT_NN_OFF 259
#define OUT_AE_IDX (OUT_NN_OFF + KK * BS)  // 3277059

__global__ __launch_bounds__(256) void tvn_kernel(const float* __restrict__ tv,
                                                  float* __restrict__ tvn) {
  __shared__ float red[256];
  const int k = blockIdx.x, t = threadIdx.x;
  float v = tv[t * KK + k];
  red[t] = v * v;
  __syncthreads();
  for (int off = 128; off > 0; off >>= 1) {
    if (t < off) red[t] += red[t + off];
    __syncthreads();
  }
  float inv = 1.0f / fmaxf(sqrtf(red[0]), 1e-12f);
  tvn[t * KK + k] = v * inv;
}

__global__ __launch_bounds__(256) void far_kernel(const float* __restrict__ tvn,
                                                  float* __restrict__ out) {
  __shared__ float red[256];
  const int t = threadIdx.x;
  float rs = 0.0f;
  for (int k = 0; k < KK; ++k) rs += tvn[t * KK + k];
  red[t] = rs * rs;  // sum(G) = sum_d (rowsum_d)^2 since G = tvn^T tvn
  __syncthreads();
  for (int off = 128; off > 0; off >>= 1) {
    if (t < off) red[t] += red[t + off];
    __syncthreads();
  }
  if (t == 0) out[258] = (red[0] - (float)KK) / ((float)KK * (float)KK);
}

__global__ __launch_bounds__(256) void main_kernel(
    const float* __restrict__ f_input, const float* __restrict__ tvn,
    const float* __restrict__ rec1, const float* __restrict__ rec2,
    float* __restrict__ out_nn, float* __restrict__ tpn_t,
    float* __restrict__ predacc, float* __restrict__ ae_acc) {
  // Xs: phase1-3 X[d][ts] stride 33 (bank-conflict-free); phase4-5 R1t[h][ts] stride 36 (16B aligned)
  __shared__ __align__(16) float Xs[DD * 36];
  __shared__ float NN[TS * 52];               // am then nn, [ts][k]
  __shared__ __align__(16) float NNt[KK * 36]; // nn transposed [k][ts] for b128 reads
  __shared__ float invn[TS];
  __shared__ float red[256];

  const int blk = blockIdx.x;
  const int b = blk >> 4;
  const int s0 = (blk & 15) * TS;
  const int t = threadIdx.x;
  const float* fb = f_input + (size_t)b * DD * SS;

  // ---- phase 1: stage X tile (coalesced float4) ----
  for (int i = t; i < DD * TS / 4; i += 256) {  // 2048 float4s
    const int d = i >> 3, q = i & 7;
    const float4 v = *(const float4*)(fb + (size_t)d * SS + s0 + q * 4);
    float* xp = &Xs[d * 33 + q * 4];
    xp[0] = v.x; xp[1] = v.y; xp[2] = v.z; xp[3] = v.w;
  }
  __syncthreads();

  // ---- phase 2: per-s norms ----
  {
    const int ts = t & 31, part = t >> 5;
    float s2 = 0.0f;
    #pragma unroll 8
    for (int j = 0; j < 32; ++j) {
      float v = Xs[(part * 32 + j) * 33 + ts];
      s2 += v * v;
    }
    red[t] = s2;
  }
  __syncthreads();
  if (t < TS) {
    float s2 = 0.0f;
    for (int p = 0; p < 8; ++p) s2 += red[p * 32 + t];
    invn[t] = 1.0f / fmaxf(sqrtf(s2), 1e-12f);
  }
  __syncthreads();

  // ---- phase 3: tp = x . tvn ; mask ; am ----
  {
    const int ts = t & 31, kb = t >> 5;
    float acc[7];
    int koff[7];
    bool kval[7];
    #pragma unroll
    for (int j = 0; j < 7; ++j) {
      acc[j] = 0.0f;
      int k = kb + 8 * j;
      kval[j] = (k < KK);
      koff[j] = kval[j] ? k : (KK - 1);
    }
    #pragma unroll 2
    for (int d = 0; d < DD; ++d) {
      const float xv = Xs[d * 33 + ts];
      const float* tp = tvn + d * KK;
      #pragma unroll
      for (int j = 0; j < 7; ++j) acc[j] += xv * tp[koff[j]];
    }
    const size_t bs = (size_t)b * SS + s0 + ts;
    #pragma unroll
    for (int j = 0; j < 7; ++j) {
      if (kval[j]) {
        const int k = kb + 8 * j;
        const float tpv = acc[j];
        const float tpnv = tpv * invn[ts];
        tpn_t[(size_t)k * BS + bs] = tpnv;
        NN[ts * 52 + k] = (tpnv > 0.3f) ? tpv : 0.0f;
      }
    }
  }
  __syncthreads();

  // ---- per-s sum over k, inverse denominator ----
  if (t < TS) {
    float sm = 0.0f;
    for (int k = 0; k < KK; ++k) sm += NN[t * 52 + k];
    red[t] = 1.0f / (sm + 0.001f + 1e-8f);
  }
  __syncthreads();

  // ---- normalize: nn; store row-major + transposed ----
  for (int p = t; p < TS * KK; p += 256) {
    const int ts = p & 31, k = p >> 5;
    const float nn = NN[ts * 52 + k] * red[ts];
    NN[ts * 52 + k] = nn;
    NNt[k * 36 + ts] = nn;
  }
  __syncthreads();

  // ---- write topic_prob_nn output (coalesced row-major) ----
  {
    float* ob = out_nn + ((size_t)b * SS + s0) * KK;
    for (int p = t; p < TS * KK; p += 256) {
      const int ts = p / KK, k = p - ts * KK;
      ob[p] = NN[ts * 52 + k];
    }
  }

  // ---- phase 4: r1[h=t][ts] = relu(nn . rec1), store transposed into Xs ----
  {
    float acc[TS];
    #pragma unroll
    for (int i = 0; i < TS; ++i) acc[i] = 0.0f;
    for (int k = 0; k < KK; ++k) {
      const float r = rec1[k * HH + t];
      const float4* np = (const float4*)&NNt[k * 36];
      #pragma unroll
      for (int q = 0; q < 8; ++q) {
        const float4 nv = np[q];
        acc[q * 4 + 0] += nv.x * r;
        acc[q * 4 + 1] += nv.y * r;
        acc[q * 4 + 2] += nv.z * r;
        acc[q * 4 + 3] += nv.w * r;
      }
    }
    #pragma unroll
    for (int i = 0; i < TS; ++i) Xs[t * 36 + i] = fmaxf(acc[i], 0.0f);
  }
  __syncthreads();

  // ---- phase 5: r2 = r1 @ rec2, register-tiled 4(ts) x 8(d) ----
  {
    const int tx = t & 31, ty = t >> 5;
    const int d0 = tx * 8, ts0 = ty * 4;
    float acc2[4][8];
    #pragma unroll
    for (int i = 0; i < 4; ++i)
      #pragma unroll
      for (int j = 0; j < 8; ++j) acc2[i][j] = 0.0f;

    #pragma unroll 2
    for (int h = 0; h < HH; ++h) {
      const float4 b0 = *(const float4*)(rec2 + h * DD + d0);
      const float4 b1 = *(const float4*)(rec2 + h * DD + d0 + 4);
      const float4 a = *(const float4*)(&Xs[h * 36 + ts0]);
      const float av[4] = {a.x, a.y, a.z, a.w};
      const float bv[8] = {b0.x, b0.y, b0.z, b0.w, b1.x, b1.y, b1.z, b1.w};
      #pragma unroll
      for (int i = 0; i < 4; ++i)
        #pragma unroll
        for (int j = 0; j < 8; ++j) acc2[i][j] += av[i] * bv[j];
    }

    // pred accumulation: sum over ts
    #pragma unroll
    for (int j = 0; j < 8; ++j) {
      const float s = acc2[0][j] + acc2[1][j] + acc2[2][j] + acc2[3][j];
      atomicAdd(&predacc[b * DD + d0 + j], s);
    }

    // ae: reload x (L1-served), e = sum (x_n - r2)^2
    float e = 0.0f;
    #pragma unroll
    for (int j = 0; j < 8; ++j) {
      const float4 xq = *(const float4*)(fb + (size_t)(d0 + j) * SS + s0 + ts0);
      const float xv[4] = {xq.x, xq.y, xq.z, xq.w};
      #pragma unroll
      for (int i = 0; i < 4; ++i) {
        const float diff = xv[i] * invn[ts0 + i] - acc2[i][j];
        e += diff * diff;
      }
    }
    red[t] = e;
    __syncthreads();
    for (int off = 128; off > 0; off >>= 1) {
      if (t < off) red[t] += red[t + off];
      __syncthreads();
    }
    if (t == 0) atomicAdd(ae_acc, red[0]);
  }
}

// exact top-32 mean per concept row via bitwise binary search on order-preserving keys
__global__ __launch_bounds__(256) void topk_kernel(const float* __restrict__ tpn_t,
                                                   float* __restrict__ sim_acc) {
  __shared__ int ired[256];
  __shared__ float fred[256];
  const int t = threadIdx.x;
  const float* row = tpn_t + (size_t)blockIdx.x * BS;

  unsigned T = 0;
  for (int bit = 31; bit >= 0; --bit) {
    const unsigned cand = T | (1u << bit);
    int c = 0;
    for (int i = t; i < BS; i += 256) {
      const unsigned u = __float_as_uint(row[i]);
      const unsigned key = (u & 0x80000000u) ? ~u : (u | 0x80000000u);
      c += (key >= cand) ? 1 : 0;
    }
    ired[t] = c;
    __syncthreads();
    for (int off = 128; off > 0; off >>= 1) {
      if (t < off) ired[t] += ired[t + off];
      __syncthreads();
    }
    if (ired[0] >= 32) T = cand;
    __syncthreads();
  }
  // sum of strictly-greater values; ties at the 32nd value handled exactly
  float s = 0.0f;
  int cgt = 0;
  for (int i = t; i < BS; i += 256) {
    const float f = row[i];
    const unsigned u = __float_as_uint(f);
    const unsigned key = (u & 0x80000000u) ? ~u : (u | 0x80000000u);
    if (key > T) { s += f; cgt += 1; }
  }
  ired[t] = cgt;
  fred[t] = s;
  __syncthreads();
  for (int off = 128; off > 0; off >>= 1) {
    if (t < off) { ired[t] += ired[t + off]; fred[t] += fred[t + off]; }
    __syncthreads();
  }
  if (t == 0) {
    const unsigned u = (T & 0x80000000u) ? (T & 0x7FFFFFFFu) : ~T;
    const float vT = __uint_as_float(u);
    atomicAdd(sim_acc, fred[0] + (float)(32 - ired[0]) * vT);
  }
}

__global__ __launch_bounds__(256) void finalize_kernel(
    const float* __restrict__ predacc, const float* __restrict__ Wc,
    const float* __restrict__ bc, const float* __restrict__ ae_acc,
    const float* __restrict__ sim_acc, float* __restrict__ out) {
  const int t = threadIdx.x;
  const int b = t >> 1, c = t & 1;
  float s = 0.0f;
  for (int d = 0; d < DD; ++d) s += predacc[b * DD + d] * Wc[d * 2 + c];
  out[t] = s * (1.0f / (float)SS) + bc[c];
  if (t == 0) {
    out[256] = 0.0f;
    out[257] = -(*sim_acc) * (1.0f / (float)(KK * 32));
    out[OUT_AE_IDX] = (*ae_acc) * (1.0f / ((float)BB * (float)SS * (float)DD));
  }
}

extern "C" void kernel_launch(void* const* d_in, const int* in_sizes, int n_in,
                              void* d_out, int out_size, void* d_ws, size_t ws_size,
                              hipStream_t stream) {
  (void)in_sizes; (void)n_in; (void)out_size; (void)ws_size;
  const float* f_input = (const float*)d_in[0];
  // d_in[1] = targets (unused by reference outputs)
  const float* tv = (const float*)d_in[2];
  const float* rec1 = (const float*)d_in[3];
  const float* rec2 = (const float*)d_in[4];
  const float* Wc = (const float*)d_in[5];
  const float* bc = (const float*)d_in[6];
  // d_in[7] = causal (unused)

  float* out = (float*)d_out;
  float* ws = (float*)d_ws;
  float* tvn = ws + TVN_OFF;
  float* tpn_t = ws + TPNT_OFF;
  float* predacc = ws + PRED_OFF;
  float* ae_acc = ws + AE_OFF;
  float* sim_acc = ws + SIM_OFF;

  // zero the accumulators (ws is re-poisoned to 0xAA before every launch)
  hipMemsetAsync(predacc, 0, (BB * DD + 2) * sizeof(float), stream);

  tvn_kernel<<<KK, 256, 0, stream>>>(tv, tvn);
  far_kernel<<<1, 256, 0, stream>>>(tvn, out);
  main_kernel<<<NBLK, 256, 0, stream>>>(f_input, tvn, rec1, rec2,
                                        out + OUT_NN_OFF, tpn_t, predacc, ae_acc);
  topk_kernel<<<KK, 256, 0, stream>>>(tpn_t, sim_acc);
  finalize_kernel<<<1, 256, 0, stream>>>(predacc, Wc, bc, ae_acc, sim_acc, out);
}

// Round 2
// 535.860 us; speedup vs baseline: 2.2057x; 2.2057x over previous
//
#include <hip/hip_runtime.h>
#include <math.h>

#define BB 128
#define DD 256
#define SS 512
#define KK 50
#define HH 256
#define TS 32
#define NTILE (SS / TS)       // 16
#define NBLK (BB * NTILE)     // 2048
#define BS (BB * SS)          // 65536

#define CHUNK 1024
#define NCH (BS / CHUNK)      // 64 chunks per concept
#define TOPK 32

// workspace layout (float offsets)
#define TVN_OFF 0
#define TPNT_OFF (TVN_OFF + DD * KK)     // 12800
#define PRED_OFF (TPNT_OFF + KK * BS)
#define AE_OFF (PRED_OFF + BB * DD)
#define SIM_OFF (AE_OFF + 1)
#define CAND_OFF (SIM_OFF + 1)           // KK * NCH * TOPK = 102400 floats

// out layout: pred[0:256), 0.0@256, sim@257, far@258, nn[259:259+3276800), ae@3277059
#define OUT_NN_OFF 259
#define OUT_AE_IDX (OUT_NN_OFF + KK * BS)  // 3277059

__device__ __forceinline__ unsigned fkey(float f) {
  unsigned u = __float_as_uint(f);
  return (u & 0x80000000u) ? ~u : (u | 0x80000000u);
}
__device__ __forceinline__ float keyval(unsigned T) {
  unsigned u = (T & 0x80000000u) ? (T & 0x7FFFFFFFu) : ~T;
  return __uint_as_float(u);
}

__global__ __launch_bounds__(256) void tvn_kernel(const float* __restrict__ tv,
                                                  float* __restrict__ tvn) {
  __shared__ float red[256];
  const int k = blockIdx.x, t = threadIdx.x;
  float v = tv[t * KK + k];
  red[t] = v * v;
  __syncthreads();
  for (int off = 128; off > 0; off >>= 1) {
    if (t < off) red[t] += red[t + off];
    __syncthreads();
  }
  float inv = 1.0f / fmaxf(sqrtf(red[0]), 1e-12f);
  tvn[t * KK + k] = v * inv;
}

__global__ __launch_bounds__(256) void far_kernel(const float* __restrict__ tvn,
                                                  float* __restrict__ out) {
  __shared__ float red[256];
  const int t = threadIdx.x;
  float rs = 0.0f;
  for (int k = 0; k < KK; ++k) rs += tvn[t * KK + k];
  red[t] = rs * rs;  // sum(G) = sum_d (rowsum_d)^2 since G = tvn^T tvn
  __syncthreads();
  for (int off = 128; off > 0; off >>= 1) {
    if (t < off) red[t] += red[t + off];
    __syncthreads();
  }
  if (t == 0) out[258] = (red[0] - (float)KK) / ((float)KK * (float)KK);
}

__global__ __launch_bounds__(256) void main_kernel(
    const float* __restrict__ f_input, const float* __restrict__ tvn,
    const float* __restrict__ rec1, const float* __restrict__ rec2,
    float* __restrict__ out_nn, float* __restrict__ tpn_t,
    float* __restrict__ predacc, float* __restrict__ ae_acc) {
  // Xs: phase1-3 X[d][ts] stride 33 (bank-conflict-free); phase4-5 R1t[h][ts] stride 36 (16B aligned)
  __shared__ __align__(16) float Xs[DD * 36];
  __shared__ float NN[TS * 52];               // am then nn, [ts][k]
  __shared__ __align__(16) float NNt[KK * 36]; // nn transposed [k][ts] for b128 reads
  __shared__ float invn[TS];
  __shared__ float red[256];

  const int blk = blockIdx.x;
  const int b = blk >> 4;
  const int s0 = (blk & 15) * TS;
  const int t = threadIdx.x;
  const float* fb = f_input + (size_t)b * DD * SS;

  // ---- phase 1: stage X tile (coalesced float4) ----
  for (int i = t; i < DD * TS / 4; i += 256) {  // 2048 float4s
    const int d = i >> 3, q = i & 7;
    const float4 v = *(const float4*)(fb + (size_t)d * SS + s0 + q * 4);
    float* xp = &Xs[d * 33 + q * 4];
    xp[0] = v.x; xp[1] = v.y; xp[2] = v.z; xp[3] = v.w;
  }
  __syncthreads();

  // ---- phase 2: per-s norms ----
  {
    const int ts = t & 31, part = t >> 5;
    float s2 = 0.0f;
    #pragma unroll 8
    for (int j = 0; j < 32; ++j) {
      float v = Xs[(part * 32 + j) * 33 + ts];
      s2 += v * v;
    }
    red[t] = s2;
  }
  __syncthreads();
  if (t < TS) {
    float s2 = 0.0f;
    for (int p = 0; p < 8; ++p) s2 += red[p * 32 + t];
    invn[t] = 1.0f / fmaxf(sqrtf(s2), 1e-12f);
  }
  __syncthreads();

  // ---- phase 3: tp = x . tvn ; mask ; am ----
  {
    const int ts = t & 31, kb = t >> 5;
    float acc[7];
    int koff[7];
    bool kval[7];
    #pragma unroll
    for (int j = 0; j < 7; ++j) {
      acc[j] = 0.0f;
      int k = kb + 8 * j;
      kval[j] = (k < KK);
      koff[j] = kval[j] ? k : (KK - 1);
    }
    #pragma unroll 2
    for (int d = 0; d < DD; ++d) {
      const float xv = Xs[d * 33 + ts];
      const float* tp = tvn + d * KK;
      #pragma unroll
      for (int j = 0; j < 7; ++j) acc[j] += xv * tp[koff[j]];
    }
    const size_t bs = (size_t)b * SS + s0 + ts;
    #pragma unroll
    for (int j = 0; j < 7; ++j) {
      if (kval[j]) {
        const int k = kb + 8 * j;
        const float tpv = acc[j];
        const float tpnv = tpv * invn[ts];
        tpn_t[(size_t)k * BS + bs] = tpnv;
        NN[ts * 52 + k] = (tpnv > 0.3f) ? tpv : 0.0f;
      }
    }
  }
  __syncthreads();

  // ---- per-s sum over k, inverse denominator ----
  if (t < TS) {
    float sm = 0.0f;
    for (int k = 0; k < KK; ++k) sm += NN[t * 52 + k];
    red[t] = 1.0f / (sm + 0.001f + 1e-8f);
  }
  __syncthreads();

  // ---- normalize: nn; store row-major + transposed ----
  for (int p = t; p < TS * KK; p += 256) {
    const int ts = p & 31, k = p >> 5;
    const float nn = NN[ts * 52 + k] * red[ts];
    NN[ts * 52 + k] = nn;
    NNt[k * 36 + ts] = nn;
  }
  __syncthreads();

  // ---- write topic_prob_nn output (coalesced row-major) ----
  {
    float* ob = out_nn + ((size_t)b * SS + s0) * KK;
    for (int p = t; p < TS * KK; p += 256) {
      const int ts = p / KK, k = p - ts * KK;
      ob[p] = NN[ts * 52 + k];
    }
  }

  // ---- phase 4: r1[h=t][ts] = relu(nn . rec1), store transposed into Xs ----
  {
    float acc[TS];
    #pragma unroll
    for (int i = 0; i < TS; ++i) acc[i] = 0.0f;
    for (int k = 0; k < KK; ++k) {
      const float r = rec1[k * HH + t];
      const float4* np = (const float4*)&NNt[k * 36];
      #pragma unroll
      for (int q = 0; q < 8; ++q) {
        const float4 nv = np[q];
        acc[q * 4 + 0] += nv.x * r;
        acc[q * 4 + 1] += nv.y * r;
        acc[q * 4 + 2] += nv.z * r;
        acc[q * 4 + 3] += nv.w * r;
      }
    }
    #pragma unroll
    for (int i = 0; i < TS; ++i) Xs[t * 36 + i] = fmaxf(acc[i], 0.0f);
  }
  __syncthreads();

  // ---- phase 5: r2 = r1 @ rec2, register-tiled 4(ts) x 8(d) ----
  {
    const int tx = t & 31, ty = t >> 5;
    const int d0 = tx * 8, ts0 = ty * 4;
    float acc2[4][8];
    #pragma unroll
    for (int i = 0; i < 4; ++i)
      #pragma unroll
      for (int j = 0; j < 8; ++j) acc2[i][j] = 0.0f;

    #pragma unroll 2
    for (int h = 0; h < HH; ++h) {
      const float4 b0 = *(const float4*)(rec2 + h * DD + d0);
      const float4 b1 = *(const float4*)(rec2 + h * DD + d0 + 4);
      const float4 a = *(const float4*)(&Xs[h * 36 + ts0]);
      const float av[4] = {a.x, a.y, a.z, a.w};
      const float bv[8] = {b0.x, b0.y, b0.z, b0.w, b1.x, b1.y, b1.z, b1.w};
      #pragma unroll
      for (int i = 0; i < 4; ++i)
        #pragma unroll
        for (int j = 0; j < 8; ++j) acc2[i][j] += av[i] * bv[j];
    }

    // pred accumulation: sum over ts
    #pragma unroll
    for (int j = 0; j < 8; ++j) {
      const float s = acc2[0][j] + acc2[1][j] + acc2[2][j] + acc2[3][j];
      atomicAdd(&predacc[b * DD + d0 + j], s);
    }

    // ae: reload x (L1-served), e = sum (x_n - r2)^2
    float e = 0.0f;
    #pragma unroll
    for (int j = 0; j < 8; ++j) {
      const float4 xq = *(const float4*)(fb + (size_t)(d0 + j) * SS + s0 + ts0);
      const float xv[4] = {xq.x, xq.y, xq.z, xq.w};
      #pragma unroll
      for (int i = 0; i < 4; ++i) {
        const float diff = xv[i] * invn[ts0 + i] - acc2[i][j];
        e += diff * diff;
      }
    }
    red[t] = e;
    __syncthreads();
    for (int off = 128; off > 0; off >>= 1) {
      if (t < off) red[t] += red[t + off];
      __syncthreads();
    }
    if (t == 0) atomicAdd(ae_acc, red[0]);
  }
}

// ---- level 1: per-wave exact top-32 of each 1024-element chunk ----
// grid: KK*NCH/4 blocks of 256 (4 waves); one wave per chunk; no LDS, no barriers.
__global__ __launch_bounds__(256) void topk_chunk_kernel(const float* __restrict__ tpn_t,
                                                         float* __restrict__ cand) {
  const int wave = threadIdx.x >> 6;
  const int lane = threadIdx.x & 63;
  const int gchunk = blockIdx.x * 4 + wave;   // 0 .. KK*NCH-1
  const int k = gchunk >> 6;                  // / NCH
  const int c = gchunk & (NCH - 1);
  const float* row = tpn_t + (size_t)k * BS + c * CHUNK;

  float v[16];
  unsigned key[16];
  #pragma unroll
  for (int j = 0; j < 16; ++j) {
    v[j] = row[lane + j * 64];
    key[j] = fkey(v[j]);
  }

  // bitwise binary search: T = max thresh with count(key >= T) >= 32
  unsigned T = 0;
  for (int bit = 31; bit >= 0; --bit) {
    const unsigned ct = T | (1u << bit);
    int cnt = 0;
    #pragma unroll
    for (int j = 0; j < 16; ++j) cnt += (key[j] >= ct) ? 1 : 0;
    #pragma unroll
    for (int off = 1; off < 64; off <<= 1) cnt += __shfl_xor(cnt, off);
    if (cnt >= TOPK) T = ct;
  }

  // compact strictly-greater values, then pad with value(T) to exactly 32
  int cg = 0;
  #pragma unroll
  for (int j = 0; j < 16; ++j) cg += (key[j] > T) ? 1 : 0;
  int incl = cg;
  #pragma unroll
  for (int off = 1; off < 64; off <<= 1) {
    int y = __shfl_up(incl, off);
    if (lane >= off) incl += y;
  }
  const int excl = incl - cg;
  const int total_gt = __shfl(incl, 63);

  float* cb = cand + (size_t)gchunk * TOPK;
  int pos = excl;
  #pragma unroll
  for (int j = 0; j < 16; ++j) {
    if (key[j] > T) cb[pos++] = v[j];
  }
  if (lane < TOPK - total_gt) cb[total_gt + lane] = keyval(T);
}

// ---- level 2: exact top-32 over NCH*32 = 2048 candidates per concept; 1 wave per k ----
__global__ __launch_bounds__(64) void topk_merge_kernel(const float* __restrict__ cand,
                                                        float* __restrict__ sim_acc) {
  const int lane = threadIdx.x & 63;
  const float* row = cand + (size_t)blockIdx.x * (NCH * TOPK);

  float v[32];
  unsigned key[32];
  #pragma unroll
  for (int j = 0; j < 32; ++j) {
    v[j] = row[lane + j * 64];
    key[j] = fkey(v[j]);
  }

  unsigned T = 0;
  for (int bit = 31; bit >= 0; --bit) {
    const unsigned ct = T | (1u << bit);
    int cnt = 0;
    #pragma unroll
    for (int j = 0; j < 32; ++j) cnt += (key[j] >= ct) ? 1 : 0;
    #pragma unroll
    for (int off = 1; off < 64; off <<= 1) cnt += __shfl_xor(cnt, off);
    if (cnt >= TOPK) T = ct;
  }

  float s = 0.0f;
  int cgt = 0;
  #pragma unroll
  for (int j = 0; j < 32; ++j) {
    if (key[j] > T) { s += v[j]; cgt++; }
  }
  #pragma unroll
  for (int off = 1; off < 64; off <<= 1) {
    s += __shfl_xor(s, off);
    cgt += __shfl_xor(cgt, off);
  }
  if (lane == 0) {
    atomicAdd(sim_acc, s + (float)(TOPK - cgt) * keyval(T));
  }
}

__global__ __launch_bounds__(256) void finalize_kernel(
    const float* __restrict__ predacc, const float* __restrict__ Wc,
    const float* __restrict__ bc, const float* __restrict__ ae_acc,
    const float* __restrict__ sim_acc, float* __restrict__ out) {
  const int t = threadIdx.x;
  const int b = t >> 1, c = t & 1;
  float s = 0.0f;
  for (int d = 0; d < DD; ++d) s += predacc[b * DD + d] * Wc[d * 2 + c];
  out[t] = s * (1.0f / (float)SS) + bc[c];
  if (t == 0) {
    out[256] = 0.0f;
    out[257] = -(*sim_acc) * (1.0f / (float)(KK * TOPK));
    out[OUT_AE_IDX] = (*ae_acc) * (1.0f / ((float)BB * (float)SS * (float)DD));
  }
}

extern "C" void kernel_launch(void* const* d_in, const int* in_sizes, int n_in,
                              void* d_out, int out_size, void* d_ws, size_t ws_size,
                              hipStream_t stream) {
  (void)in_sizes; (void)n_in; (void)out_size; (void)ws_size;
  const float* f_input = (const float*)d_in[0];
  // d_in[1] = targets (unused by reference outputs)
  const float* tv = (const float*)d_in[2];
  const float* rec1 = (const float*)d_in[3];
  const float* rec2 = (const float*)d_in[4];
  const float* Wc = (const float*)d_in[5];
  const float* bc = (const float*)d_in[6];
  // d_in[7] = causal (unused)

  float* out = (float*)d_out;
  float* ws = (float*)d_ws;
  float* tvn = ws + TVN_OFF;
  float* tpn_t = ws + TPNT_OFF;
  float* predacc = ws + PRED_OFF;
  float* ae_acc = ws + AE_OFF;
  float* sim_acc = ws + SIM_OFF;
  float* cand = ws + CAND_OFF;

  // zero the accumulators (ws is re-poisoned to 0xAA before every launch)
  hipMemsetAsync(predacc, 0, (BB * DD + 2) * sizeof(float), stream);

  tvn_kernel<<<KK, 256, 0, stream>>>(tv, tvn);
  far_kernel<<<1, 256, 0, stream>>>(tvn, out);
  main_kernel<<<NBLK, 256, 0, stream>>>(f_input, tvn, rec1, rec2,
                                        out + OUT_NN_OFF, tpn_t, predacc, ae_acc);
  topk_chunk_kernel<<<KK * NCH / 4, 256, 0, stream>>>(tpn_t, cand);
  topk_merge_kernel<<<KK, 64, 0, stream>>>(cand, sim_acc);
  finalize_kernel<<<1, 256, 0, stream>>>(predacc, Wc, bc, ae_acc, sim_acc, out);
}

// Round 3
// 274.880 us; speedup vs baseline: 4.2999x; 1.9494x over previous
//
#include <hip/hip_runtime.h>
#include <math.h>

#define BB 128
#define DD 256
#define SS 512
#define KK 50
#define HH 256
#define TS 32
#define NTILE (SS / TS)       // 16
#define NBLK (BB * NTILE)     // 2048
#define BS (BB * SS)          // 65536

#define CHUNK 1024
#define NCH (BS / CHUNK)      // 64 chunks per concept
#define TOPK 32

// workspace layout (float offsets)
#define TVN_OFF 0
#define TVNT_OFF (TVN_OFF + DD * KK)        // tvn transposed [k][d]
#define TPNT_OFF (TVNT_OFF + KK * DD)
#define PREDPART_OFF (TPNT_OFF + KK * BS)   // NBLK * DD floats
#define AE_OFF (PREDPART_OFF + NBLK * DD)
#define SIM_OFF (AE_OFF + 1)
#define CAND_OFF (SIM_OFF + 1)              // KK * NCH * TOPK floats

// out layout: pred[0:256), 0.0@256, sim@257, far@258, nn[259:259+3276800), ae@3277059
#define OUT_NN_OFF 259
#define OUT_AE_IDX (OUT_NN_OFF + KK * BS)  // 3277059

__device__ __forceinline__ unsigned fkey(float f) {
  unsigned u = __float_as_uint(f);
  return (u & 0x80000000u) ? ~u : (u | 0x80000000u);
}
__device__ __forceinline__ float keyval(unsigned T) {
  unsigned u = (T & 0x80000000u) ? (T & 0x7FFFFFFFu) : ~T;
  return __uint_as_float(u);
}

__global__ __launch_bounds__(256) void tvn_kernel(const float* __restrict__ tv,
                                                  float* __restrict__ tvn,
                                                  float* __restrict__ tvnT) {
  __shared__ float red[256];
  const int k = blockIdx.x, t = threadIdx.x;
  float v = tv[t * KK + k];
  red[t] = v * v;
  __syncthreads();
  for (int off = 128; off > 0; off >>= 1) {
    if (t < off) red[t] += red[t + off];
    __syncthreads();
  }
  float inv = 1.0f / fmaxf(sqrtf(red[0]), 1e-12f);
  const float nv = v * inv;
  tvn[t * KK + k] = nv;
  tvnT[k * DD + t] = nv;
}

__global__ __launch_bounds__(256) void far_kernel(const float* __restrict__ tvn,
                                                  float* __restrict__ out) {
  __shared__ float red[256];
  const int t = threadIdx.x;
  float rs = 0.0f;
  for (int k = 0; k < KK; ++k) rs += tvn[t * KK + k];
  red[t] = rs * rs;  // sum(G) = sum_d (rowsum_d)^2 since G = tvn^T tvn
  __syncthreads();
  for (int off = 128; off > 0; off >>= 1) {
    if (t < off) red[t] += red[t + off];
    __syncthreads();
  }
  if (t == 0) out[258] = (red[0] - (float)KK) / ((float)KK * (float)KK);
}

__global__ __launch_bounds__(256) void main_kernel(
    const float* __restrict__ f_input, const float* __restrict__ tvnT,
    const float* __restrict__ rec1, const float* __restrict__ rec2,
    float* __restrict__ out_nn, float* __restrict__ tpn_t,
    float* __restrict__ predpart, float* __restrict__ ae_acc) {
  // Xs: phase1-3 X[d][ts] stride 33 (bank-conflict-free); phase4-5 R1t[h][ts] stride 36
  __shared__ __align__(16) float Xs[DD * 36];
  __shared__ float NN[TS * 52];               // am then nn, [ts][k]
  __shared__ __align__(16) float NNt[KK * 36]; // nn transposed [k][ts]
  __shared__ float invn[TS];
  __shared__ float red[256];
  __shared__ int anyflag;

  const int blk = blockIdx.x;
  const int b = blk >> 4;
  const int s0 = (blk & 15) * TS;
  const int t = threadIdx.x;
  const float* fb = f_input + (size_t)b * DD * SS;

  if (t == 0) anyflag = 0;

  // ---- phase 1: stage X tile (coalesced float4) ----
  for (int i = t; i < DD * TS / 4; i += 256) {  // 2048 float4s
    const int d = i >> 3, q = i & 7;
    const float4 v = *(const float4*)(fb + (size_t)d * SS + s0 + q * 4);
    float* xp = &Xs[d * 33 + q * 4];
    xp[0] = v.x; xp[1] = v.y; xp[2] = v.z; xp[3] = v.w;
  }
  __syncthreads();

  // ---- phase 2: per-s norms ----
  {
    const int ts = t & 31, part = t >> 5;
    float s2 = 0.0f;
    #pragma unroll 8
    for (int j = 0; j < 32; ++j) {
      float v = Xs[(part * 32 + j) * 33 + ts];
      s2 += v * v;
    }
    red[t] = s2;
  }
  __syncthreads();
  if (t < TS) {
    float s2 = 0.0f;
    for (int p = 0; p < 8; ++p) s2 += red[p * 32 + t];
    invn[t] = 1.0f / fmaxf(sqrtf(s2), 1e-12f);
  }
  __syncthreads();

  // ---- phase 3: tp = x . tvn (vectorized over d via tvnT) ; mask ; am ----
  {
    const int ts = t & 31, kb = t >> 5;
    float acc[7];
    const float* tT[7];
    bool kval[7];
    #pragma unroll
    for (int j = 0; j < 7; ++j) {
      acc[j] = 0.0f;
      const int k = kb + 8 * j;
      kval[j] = (k < KK);
      tT[j] = tvnT + (size_t)(kval[j] ? k : (KK - 1)) * DD;
    }
    #pragma unroll 2
    for (int d0 = 0; d0 < DD; d0 += 4) {
      const float x0 = Xs[(d0 + 0) * 33 + ts];
      const float x1 = Xs[(d0 + 1) * 33 + ts];
      const float x2 = Xs[(d0 + 2) * 33 + ts];
      const float x3 = Xs[(d0 + 3) * 33 + ts];
      #pragma unroll
      for (int j = 0; j < 7; ++j) {
        const float4 tv4 = *(const float4*)(tT[j] + d0);
        // same per-acc accumulation order as scalar d-loop (bit-exact mask)
        acc[j] += x0 * tv4.x;
        acc[j] += x1 * tv4.y;
        acc[j] += x2 * tv4.z;
        acc[j] += x3 * tv4.w;
      }
    }
    const size_t bs = (size_t)b * SS + s0 + ts;
    #pragma unroll
    for (int j = 0; j < 7; ++j) {
      if (kval[j]) {
        const int k = kb + 8 * j;
        const float tpv = acc[j];
        const float tpnv = tpv * invn[ts];
        tpn_t[(size_t)k * BS + bs] = tpnv;
        NN[ts * 52 + k] = (tpnv > 0.3f) ? tpv : 0.0f;
      }
    }
  }
  __syncthreads();

  // ---- per-s sum over k, inverse denominator; detect any surviving mask ----
  if (t < TS) {
    float sm = 0.0f;
    for (int k = 0; k < KK; ++k) sm += NN[t * 52 + k];
    if (sm > 0.0f) anyflag = 1;  // am entries are strictly positive when present
    red[t] = 1.0f / (sm + 0.001f + 1e-8f);
  }
  __syncthreads();

  // ---- normalize: nn; store row-major + transposed ----
  for (int p = t; p < TS * KK; p += 256) {
    const int ts = p & 31, k = p >> 5;
    const float nn = NN[ts * 52 + k] * red[ts];
    NN[ts * 52 + k] = nn;
    NNt[k * 36 + ts] = nn;
  }
  __syncthreads();

  // ---- write topic_prob_nn output (coalesced row-major) ----
  {
    float* ob = out_nn + ((size_t)b * SS + s0) * KK;
    for (int p = t; p < TS * KK; p += 256) {
      const int ts = p / KK, k = p - ts * KK;
      ob[p] = NN[ts * 52 + k];
    }
  }

  // ---- fast path: whole tile masked out -> r1=r2=0 exactly ----
  // pred partial = 0; ae contribution = sum_s sum_d x_n^2 = 32.0 (exact to fp rounding)
  if (!anyflag) {
    predpart[(size_t)blk * DD + t] = 0.0f;
    if (t == 0) atomicAdd(ae_acc, 32.0f);
    return;
  }

  // ---- phase 4: r1[h=t][ts] = relu(nn . rec1), store transposed into Xs ----
  {
    float acc[TS];
    #pragma unroll
    for (int i = 0; i < TS; ++i) acc[i] = 0.0f;
    for (int k = 0; k < KK; ++k) {
      const float r = rec1[k * HH + t];
      const float4* np = (const float4*)&NNt[k * 36];
      #pragma unroll
      for (int q = 0; q < 8; ++q) {
        const float4 nv = np[q];
        acc[q * 4 + 0] += nv.x * r;
        acc[q * 4 + 1] += nv.y * r;
        acc[q * 4 + 2] += nv.z * r;
        acc[q * 4 + 3] += nv.w * r;
      }
    }
    #pragma unroll
    for (int i = 0; i < TS; ++i) Xs[t * 36 + i] = fmaxf(acc[i], 0.0f);
  }
  __syncthreads();

  // ---- phase 5: r2 = r1 @ rec2, register-tiled 4(ts) x 8(d) ----
  {
    const int tx = t & 31, ty = t >> 5;
    const int d0 = tx * 8, ts0 = ty * 4;
    float acc2[4][8];
    #pragma unroll
    for (int i = 0; i < 4; ++i)
      #pragma unroll
      for (int j = 0; j < 8; ++j) acc2[i][j] = 0.0f;

    #pragma unroll 2
    for (int h = 0; h < HH; ++h) {
      const float4 b0 = *(const float4*)(rec2 + h * DD + d0);
      const float4 b1 = *(const float4*)(rec2 + h * DD + d0 + 4);
      const float4 a = *(const float4*)(&Xs[h * 36 + ts0]);
      const float av[4] = {a.x, a.y, a.z, a.w};
      const float bv[8] = {b0.x, b0.y, b0.z, b0.w, b1.x, b1.y, b1.z, b1.w};
      #pragma unroll
      for (int i = 0; i < 4; ++i)
        #pragma unroll
        for (int j = 0; j < 8; ++j) acc2[i][j] += av[i] * bv[j];
    }

    // pred partial: sum over ts within block, no atomics
    __syncthreads();           // everyone done reading Xs (R1t)
    float* pm = Xs;            // reuse as pm[8][256]
    #pragma unroll
    for (int j = 0; j < 8; ++j) {
      pm[ty * DD + d0 + j] = acc2[0][j] + acc2[1][j] + acc2[2][j] + acc2[3][j];
    }
    __syncthreads();
    {
      float s = 0.0f;
      #pragma unroll
      for (int r = 0; r < 8; ++r) s += pm[r * DD + t];
      predpart[(size_t)blk * DD + t] = s;
    }

    // ae: reload x (L1-served), e = sum (x_n - r2)^2
    float e = 0.0f;
    #pragma unroll
    for (int j = 0; j < 8; ++j) {
      const float4 xq = *(const float4*)(fb + (size_t)(d0 + j) * SS + s0 + ts0);
      const float xv[4] = {xq.x, xq.y, xq.z, xq.w};
      #pragma unroll
      for (int i = 0; i < 4; ++i) {
        const float diff = xv[i] * invn[ts0 + i] - acc2[i][j];
        e += diff * diff;
      }
    }
    red[t] = e;
    __syncthreads();
    for (int off = 128; off > 0; off >>= 1) {
      if (t < off) red[t] += red[t + off];
      __syncthreads();
    }
    if (t == 0) atomicAdd(ae_acc, red[0]);
  }
}

// ---- level 1: per-wave exact top-32 of each 1024-element chunk ----
__global__ __launch_bounds__(256) void topk_chunk_kernel(const float* __restrict__ tpn_t,
                                                         float* __restrict__ cand) {
  const int wave = threadIdx.x >> 6;
  const int lane = threadIdx.x & 63;
  const int gchunk = blockIdx.x * 4 + wave;   // 0 .. KK*NCH-1
  const int k = gchunk >> 6;                  // / NCH
  const int c = gchunk & (NCH - 1);
  const float* row = tpn_t + (size_t)k * BS + c * CHUNK;

  float v[16];
  unsigned key[16];
  #pragma unroll
  for (int j = 0; j < 16; ++j) {
    v[j] = row[lane + j * 64];
    key[j] = fkey(v[j]);
  }

  unsigned T = 0;
  for (int bit = 31; bit >= 0; --bit) {
    const unsigned ct = T | (1u << bit);
    int cnt = 0;
    #pragma unroll
    for (int j = 0; j < 16; ++j) cnt += (key[j] >= ct) ? 1 : 0;
    #pragma unroll
    for (int off = 1; off < 64; off <<= 1) cnt += __shfl_xor(cnt, off);
    if (cnt >= TOPK) T = ct;
  }

  int cg = 0;
  #pragma unroll
  for (int j = 0; j < 16; ++j) cg += (key[j] > T) ? 1 : 0;
  int incl = cg;
  #pragma unroll
  for (int off = 1; off < 64; off <<= 1) {
    int y = __shfl_up(incl, off);
    if (lane >= off) incl += y;
  }
  const int excl = incl - cg;
  const int total_gt = __shfl(incl, 63);

  float* cb = cand + (size_t)gchunk * TOPK;
  int pos = excl;
  #pragma unroll
  for (int j = 0; j < 16; ++j) {
    if (key[j] > T) cb[pos++] = v[j];
  }
  if (lane < TOPK - total_gt) cb[total_gt + lane] = keyval(T);
}

// ---- level 2: exact top-32 over 2048 candidates per concept; 1 wave per k ----
__global__ __launch_bounds__(64) void topk_merge_kernel(const float* __restrict__ cand,
                                                        float* __restrict__ sim_acc) {
  const int lane = threadIdx.x & 63;
  const float* row = cand + (size_t)blockIdx.x * (NCH * TOPK);

  float v[32];
  unsigned key[32];
  #pragma unroll
  for (int j = 0; j < 32; ++j) {
    v[j] = row[lane + j * 64];
    key[j] = fkey(v[j]);
  }

  unsigned T = 0;
  for (int bit = 31; bit >= 0; --bit) {
    const unsigned ct = T | (1u << bit);
    int cnt = 0;
    #pragma unroll
    for (int j = 0; j < 32; ++j) cnt += (key[j] >= ct) ? 1 : 0;
    #pragma unroll
    for (int off = 1; off < 64; off <<= 1) cnt += __shfl_xor(cnt, off);
    if (cnt >= TOPK) T = ct;
  }

  float s = 0.0f;
  int cgt = 0;
  #pragma unroll
  for (int j = 0; j < 32; ++j) {
    if (key[j] > T) { s += v[j]; cgt++; }
  }
  #pragma unroll
  for (int off = 1; off < 64; off <<= 1) {
    s += __shfl_xor(s, off);
    cgt += __shfl_xor(cgt, off);
  }
  if (lane == 0) {
    atomicAdd(sim_acc, s + (float)(TOPK - cgt) * keyval(T));
  }
}

__global__ __launch_bounds__(256) void finalize_kernel(
    const float* __restrict__ predpart, const float* __restrict__ Wc,
    const float* __restrict__ bc, const float* __restrict__ ae_acc,
    const float* __restrict__ sim_acc, float* __restrict__ out) {
  __shared__ float r0[256], r1[256];
  const int b = blockIdx.x, t = threadIdx.x;
  float s = 0.0f;
  for (int i = 0; i < NTILE; ++i) s += predpart[((size_t)(b * NTILE + i)) * DD + t];
  r0[t] = s * Wc[t * 2 + 0];
  r1[t] = s * Wc[t * 2 + 1];
  __syncthreads();
  for (int off = 128; off > 0; off >>= 1) {
    if (t < off) { r0[t] += r0[t + off]; r1[t] += r1[t + off]; }
    __syncthreads();
  }
  if (t == 0) {
    out[b * 2 + 0] = r0[0] * (1.0f / (float)SS) + bc[0];
    out[b * 2 + 1] = r1[0] * (1.0f / (float)SS) + bc[1];
    if (b == 0) {
      out[256] = 0.0f;
      out[257] = -(*sim_acc) * (1.0f / (float)(KK * TOPK));
      out[OUT_AE_IDX] = (*ae_acc) * (1.0f / ((float)BB * (float)SS * (float)DD));
    }
  }
}

extern "C" void kernel_launch(void* const* d_in, const int* in_sizes, int n_in,
                              void* d_out, int out_size, void* d_ws, size_t ws_size,
                              hipStream_t stream) {
  (void)in_sizes; (void)n_in; (void)out_size; (void)ws_size;
  const float* f_input = (const float*)d_in[0];
  const float* tv = (const float*)d_in[2];
  const float* rec1 = (const float*)d_in[3];
  const float* rec2 = (const float*)d_in[4];
  const float* Wc = (const float*)d_in[5];
  const float* bc = (const float*)d_in[6];

  float* out = (float*)d_out;
  float* ws = (float*)d_ws;
  float* tvn = ws + TVN_OFF;
  float* tvnT = ws + TVNT_OFF;
  float* tpn_t = ws + TPNT_OFF;
  float* predpart = ws + PREDPART_OFF;
  float* ae_acc = ws + AE_OFF;
  float* sim_acc = ws + SIM_OFF;
  float* cand = ws + CAND_OFF;

  // zero the two scalar accumulators (ws re-poisoned to 0xAA before every launch)
  hipMemsetAsync(ae_acc, 0, 2 * sizeof(float), stream);

  tvn_kernel<<<KK, 256, 0, stream>>>(tv, tvn, tvnT);
  far_kernel<<<1, 256, 0, stream>>>(tvn, out);
  main_kernel<<<NBLK, 256, 0, stream>>>(f_input, tvnT, rec1, rec2,
                                        out + OUT_NN_OFF, tpn_t, predpart, ae_acc);
  topk_chunk_kernel<<<KK * NCH / 4, 256, 0, stream>>>(tpn_t, cand);
  topk_merge_kernel<<<KK, 64, 0, stream>>>(cand, sim_acc);
  finalize_kernel<<<BB, 256, 0, stream>>>(predpart, Wc, bc, ae_acc, sim_acc, out);
}